// Round 12
// baseline (126.394 us; speedup 1.0000x reference)
//
#include <hip/hip_runtime.h>

#define SN 524288   // columns of the (64, SN) view of x

typedef float f32x4 __attribute__((ext_vector_type(4)));

// ---------------- Kernel A: build Ct[c*64 + i] = C[i][c], C = [B | M21] (64 x 128) ---
__global__ __launch_bounds__(256) void k_buildC(const float* __restrict__ L,
                                                const float* __restrict__ R,
                                                float* __restrict__ Ct) {
  __shared__ float4 Ls[4096];  // L (128x128) XOR-swizzled in float4 units
  const float4* L4 = (const float4*)L;
  #pragma unroll
  for (int it = 0; it < 16; ++it) {
    int idx = threadIdx.x + it * 256;
    int row = idx >> 5, t4 = idx & 31;
    Ls[(row << 5) + (t4 ^ (row & 7))] = L4[idx];
  }
  __syncthreads();
  int g = blockIdx.x * 256 + threadIdx.x;  // 0..8191
  int c = g >> 6;                          // column of C, uniform per wave
  int i = g & 63;                          // row of C = lane
  if (c < 64) {
    float d1 = 0.f, d2 = 0.f;
    #pragma unroll
    for (int t4 = 0; t4 < 32; ++t4) {
      float4 a1 = Ls[(i << 5) + (t4 ^ (i & 7))];
      float4 b1 = Ls[(c << 5) + (t4 ^ (c & 7))];
      float4 a2 = Ls[((64 + i) << 5) + (t4 ^ (i & 7))];
      float4 b2 = Ls[((64 + c) << 5) + (t4 ^ (c & 7))];
      d1 += a1.x * b1.x + a1.y * b1.y + a1.z * b1.z + a1.w * b1.w;
      d2 += a2.x * b2.x + a2.y * b2.y + a2.z * b2.z + a2.w * b2.w;
    }
    float val = 2.0f * (d1 + d2 + R[i * 64 + c] - R[c * 64 + i]);
    if (i == c) val += 4e-8f;
    Ct[c * 64 + i] = val;
  } else {
    int jj = c - 64;
    float d = 0.f;
    #pragma unroll
    for (int t4 = 0; t4 < 32; ++t4) {
      float4 a = Ls[(i << 5) + (t4 ^ (i & 7))];
      float4 b = Ls[((64 + jj) << 5) + (t4 ^ (jj & 7))];
      d += a.x * b.x + a.y * b.y + a.z * b.z + a.w * b.w;
    }
    Ct[c * 64 + i] = d;
  }
}

// ---------------- Kernel B: Gauss-Jordan solve B A = M21 --------------------------
// Emits AtW[(h*64 + k)*16 + ii] = A[16h + ii][k]  (k_apply's dwordx16 scalar layout).
__global__ __launch_bounds__(256) void k_solve(const float* __restrict__ Ct,
                                               float* __restrict__ AtW) {
  __shared__ float colbuf[2][64];
  __shared__ __align__(16) float rowbuf[2][128];
  const int r = threadIdx.x & 63;
  const int cgrp = threadIdx.x >> 6;
  float creg[32];
  #pragma unroll
  for (int cc = 0; cc < 32; ++cc)
    creg[cc] = Ct[(cgrp * 32 + cc) * 64 + r];
  #pragma unroll
  for (int p = 0; p < 64; ++p) {
    const int pb = p & 1, pc = p >> 5, pi = p & 31;
    if (cgrp == pc) colbuf[pb][r] = creg[pi];
    if (r == p) {
      #pragma unroll
      for (int cc = 0; cc < 32; ++cc) rowbuf[pb][cgrp * 32 + cc] = creg[cc];
    }
    __syncthreads();
    const float f = colbuf[pb][r];
    const float inv = 1.0f / colbuf[pb][p];
    if (r == p) {
      #pragma unroll
      for (int cc = 0; cc < 32; ++cc) creg[cc] *= inv;
    } else {
      const float gg = f * inv;
      #pragma unroll
      for (int c4 = 0; c4 < 8; ++c4) {
        const float4 pv = *(const float4*)&rowbuf[pb][cgrp * 32 + c4 * 4];
        creg[c4 * 4 + 0] -= gg * pv.x;
        creg[c4 * 4 + 1] -= gg * pv.y;
        creg[c4 * 4 + 2] -= gg * pv.z;
        creg[c4 * 4 + 3] -= gg * pv.w;
      }
    }
  }
  // creg[cc] (cgrp>=2) = A[r][k=(cgrp-2)*32+cc]
  if (cgrp >= 2) {
    #pragma unroll
    for (int cc = 0; cc < 32; ++cc) {
      int k = (cgrp - 2) * 32 + cc;
      AtW[((r >> 4) * 64 + k) * 16 + (r & 15)] = creg[cc];
    }
  }
}

// -------- Kernel C: out = A @ X, X = x viewed (64, SN) --------
// Block-synchronous data path (T14 async-STAGE split). Block = 4 waves, owns 64
// f32x4 columns (c4 = b*64 + lane) x all 64 k. x window staged in LDS in 4
// double-buffered chunks of 16 k (16 KB each): per iter, barrier -> issue next
// chunk's 4 global_load_dwordx4/thread (in flight across the compute phase) ->
// compute chunk c from LDS (ds_read_b128 sweep, conflict-free; A via scalar
// s_load_dwordx16) -> ds_write staged regs into the other buffer. One barrier
// per iter (top barrier separates iterations; writes target the buffer last
// read two iterations ago). x global traffic = read ONCE per block (the 4x
// duplicate window reads of R6-R10 now hit LDS). Wave w = output rows 16w..16w+15.
__global__ __launch_bounds__(256) void k_apply(const float* __restrict__ x,
                                               const float* __restrict__ AtW,
                                               float* __restrict__ out) {
  __shared__ f32x4 xt[2][1024];  // [buf][kk*64 + lane], 16 KB per buffer
  const int lane = threadIdx.x & 63;
  const int w = threadIdx.x >> 6;
  const int h = __builtin_amdgcn_readfirstlane(w);       // uniform i-16th
  const int c4 = blockIdx.x * 64 + lane;                 // f32x4-column of x/out
  const float* __restrict__ Ab = AtW + h * 64 * 16;      // Ab[k*16+ii] = A[16h+ii][k]
  const f32x4* x4 = (const f32x4*)x;

  f32x4 acc[16];
  #pragma unroll
  for (int il = 0; il < 16; ++il) acc[il] = (f32x4){0.f, 0.f, 0.f, 0.f};

  // prologue: stage chunk 0 (rows s*4 + w, s = 0..3)
  f32x4 st[4];
  #pragma unroll
  for (int s = 0; s < 4; ++s) st[s] = x4[(s * 4 + w) * (SN / 4) + c4];
  #pragma unroll
  for (int s = 0; s < 4; ++s) xt[0][(s * 4 + w) * 64 + lane] = st[s];

  for (int c = 0; c < 4; ++c) {
    __syncthreads();  // chunk c's ds_writes visible; all waves past chunk c-1
    if (c < 3) {      // issue chunk c+1 loads; consumed at the ds_write below
      #pragma unroll
      for (int s = 0; s < 4; ++s)
        st[s] = x4[((c + 1) * 16 + s * 4 + w) * (SN / 4) + c4];
    }
    // compute chunk c from LDS
    #pragma unroll
    for (int kk = 0; kk < 16; ++kk) {
      const f32x4 xv = xt[c & 1][kk * 64 + lane];
      const float* __restrict__ ak = Ab + (c * 16 + kk) * 16;  // s_load_dwordx16
      #pragma unroll
      for (int il = 0; il < 16; ++il)
        acc[il] += ak[il] * xv;
    }
    if (c < 3) {      // write staged chunk c+1 into the other buffer
      #pragma unroll
      for (int s = 0; s < 4; ++s)
        xt[(c + 1) & 1][(s * 4 + w) * 64 + lane] = st[s];
    }
  }

  f32x4* out4 = (f32x4*)out;
  #pragma unroll
  for (int il = 0; il < 16; ++il)
    out4[(h * 16 + il) * (SN / 4) + c4] = acc[il];
}

extern "C" void kernel_launch(void* const* d_in, const int* in_sizes, int n_in,
                              void* d_out, int out_size, void* d_ws, size_t ws_size,
                              hipStream_t stream) {
  const float* x = (const float*)d_in[0];  // 524288 x 64
  const float* L = (const float*)d_in[1];  // 128 x 128
  const float* R = (const float*)d_in[2];  // 64 x 64
  float* out = (float*)d_out;
  float* Ct  = (float*)d_ws;               // 128*64 f32 = 32 KB
  float* AtW = Ct + 128 * 64;              // 64*64 f32 = 16 KB
  k_buildC<<<32, 256, 0, stream>>>(L, R, Ct);
  k_solve<<<1, 256, 0, stream>>>(Ct, AtW);
  k_apply<<<2048, 256, 0, stream>>>(x, AtW, out);
}

// Round 14
// 107.742 us; speedup vs baseline: 1.1731x; 1.1731x over previous
//
#include <hip/hip_runtime.h>
#include <hip/hip_bf16.h>

#define SN 524288   // columns of the (64, SN) view of x

typedef float f32x4 __attribute__((ext_vector_type(4)));
typedef short bf16x8 __attribute__((ext_vector_type(8)));
typedef unsigned int u32x4 __attribute__((ext_vector_type(4)));

__device__ inline unsigned short f2bf(float v) {
  __hip_bfloat16 h = __float2bfloat16(v);
  unsigned short u; __builtin_memcpy(&u, &h, 2); return u;
}
__device__ inline float bf2f(unsigned short b) {
  unsigned u = ((unsigned)b) << 16; float f; __builtin_memcpy(&f, &u, 4); return f;
}

// ---------------- Kernel A: build Ct[c*64 + i] = C[i][c], C = [B | M21] (64 x 128) ---
__global__ __launch_bounds__(256) void k_buildC(const float* __restrict__ L,
                                                const float* __restrict__ R,
                                                float* __restrict__ Ct) {
  __shared__ float4 Ls[4096];  // L (128x128) XOR-swizzled in float4 units
  const float4* L4 = (const float4*)L;
  #pragma unroll
  for (int it = 0; it < 16; ++it) {
    int idx = threadIdx.x + it * 256;
    int row = idx >> 5, t4 = idx & 31;
    Ls[(row << 5) + (t4 ^ (row & 7))] = L4[idx];
  }
  __syncthreads();
  int g = blockIdx.x * 256 + threadIdx.x;  // 0..8191
  int c = g >> 6;                          // column of C, uniform per wave
  int i = g & 63;                          // row of C = lane
  if (c < 64) {
    float d1 = 0.f, d2 = 0.f;
    #pragma unroll
    for (int t4 = 0; t4 < 32; ++t4) {
      float4 a1 = Ls[(i << 5) + (t4 ^ (i & 7))];
      float4 b1 = Ls[(c << 5) + (t4 ^ (c & 7))];
      float4 a2 = Ls[((64 + i) << 5) + (t4 ^ (i & 7))];
      float4 b2 = Ls[((64 + c) << 5) + (t4 ^ (c & 7))];
      d1 += a1.x * b1.x + a1.y * b1.y + a1.z * b1.z + a1.w * b1.w;
      d2 += a2.x * b2.x + a2.y * b2.y + a2.z * b2.z + a2.w * b2.w;
    }
    float val = 2.0f * (d1 + d2 + R[i * 64 + c] - R[c * 64 + i]);
    if (i == c) val += 4e-8f;
    Ct[c * 64 + i] = val;
  } else {
    int jj = c - 64;
    float d = 0.f;
    #pragma unroll
    for (int t4 = 0; t4 < 32; ++t4) {
      float4 a = Ls[(i << 5) + (t4 ^ (i & 7))];
      float4 b = Ls[((64 + jj) << 5) + (t4 ^ (jj & 7))];
      d += a.x * b.x + a.y * b.y + a.z * b.z + a.w * b.w;
    }
    Ct[c * 64 + i] = d;
  }
}

// ---------------- Kernel B: Gauss-Jordan solve, emit A in MFMA fragment format ----
// AF[ld*64 + f*4 + j2] (u32): lane ld = (r&15) + 16*(k'>>3); frag f = (g*2+ks)*2+part
// (g = r>>4 row-group, ks = k>>5 k-half, part 0=hi/1=lo bf16 split); word j2 packs
// bf16 pair for k' = {8*(ld>>4)+2*j2, +1}. Same (lane,elem)->k map is used for the
// B-operand in k_apply, so any hw k-permutation cancels (A/B mirror symmetry).
__global__ __launch_bounds__(256) void k_solve(const float* __restrict__ Ct,
                                               unsigned int* __restrict__ AF) {
  __shared__ float colbuf[2][64];
  __shared__ __align__(16) float rowbuf[2][128];
  const int r = threadIdx.x & 63;
  const int cgrp = threadIdx.x >> 6;
  float creg[32];
  #pragma unroll
  for (int cc = 0; cc < 32; ++cc)
    creg[cc] = Ct[(cgrp * 32 + cc) * 64 + r];
  #pragma unroll
  for (int p = 0; p < 64; ++p) {
    const int pb = p & 1, pc = p >> 5, pi = p & 31;
    if (cgrp == pc) colbuf[pb][r] = creg[pi];
    if (r == p) {
      #pragma unroll
      for (int cc = 0; cc < 32; ++cc) rowbuf[pb][cgrp * 32 + cc] = creg[cc];
    }
    __syncthreads();
    const float f = colbuf[pb][r];
    const float inv = 1.0f / colbuf[pb][p];
    if (r == p) {
      #pragma unroll
      for (int cc = 0; cc < 32; ++cc) creg[cc] *= inv;
    } else {
      const float gg = f * inv;
      #pragma unroll
      for (int c4 = 0; c4 < 8; ++c4) {
        const float4 pv = *(const float4*)&rowbuf[pb][cgrp * 32 + c4 * 4];
        creg[c4 * 4 + 0] -= gg * pv.x;
        creg[c4 * 4 + 1] -= gg * pv.y;
        creg[c4 * 4 + 2] -= gg * pv.z;
        creg[c4 * 4 + 3] -= gg * pv.w;
      }
    }
  }
  // creg[cc] (cgrp>=2) = A[r][k = (cgrp-2)*32 + cc]
  if (cgrp >= 2) {
    const int ks = cgrp - 2;
    const int g = r >> 4;
    const int rl = r & 15;
    #pragma unroll
    for (int p2 = 0; p2 < 16; ++p2) {
      const int cc = p2 * 2;
      const float v0 = creg[cc], v1 = creg[cc + 1];
      const unsigned short h0 = f2bf(v0), h1 = f2bf(v1);
      const unsigned short l0 = f2bf(v0 - bf2f(h0)), l1 = f2bf(v1 - bf2f(h1));
      const int ld = rl + 16 * (cc >> 3);
      const int j2 = (cc & 7) >> 1;
      AF[ld * 64 + ((g * 2 + ks) * 2 + 0) * 4 + j2] = ((unsigned)h1 << 16) | h0;
      AF[ld * 64 + ((g * 2 + ks) * 2 + 1) * 4 + j2] = ((unsigned)l1 << 16) | l0;
    }
  }
}

// -------- Kernel C: out = A @ X via bf16-split MFMA (3 products: AhXh+AhXl+AlXh) ---
// Block = 4 waves, 4 chunks of 64 f32-cols (256 cols/block). X chunk staged fp32 in
// LDS [64][65] (stride 65: conflict-free column reads). Per wave per chunk: wave w
// owns cols w*16+(lane&15); per ks-half: 16 ds_read_b32 (8 k-pairs), cvt to bf16
// hi/lo B-frags, 12 MFMAs into acc[4] (4 row-groups); epilogue uses verified C/D
// map (col=lane&15, row=(lane>>4)*4+reg). Double-buffered staging, T14 split:
// next chunk's 4 global_load_dwordx4 issued before compute, ds_write after.
__global__ __launch_bounds__(256) void k_apply(const float* __restrict__ x,
                                               const unsigned int* __restrict__ AF,
                                               float* __restrict__ out) {
  __shared__ float Xs[2][64 * 65];  // 2 x 16.25 KB
  const int t = threadIdx.x;
  const int lane = t & 63;
  const int w = t >> 6;
  const int l15 = lane & 15;
  const int lg = lane >> 4;          // k-group for B, row-group for C/D
  const int cb0 = blockIdx.x * 256;  // first f32 col of this block

  // A fragments: 16 x (4 dwords) = hi/lo for 4 row-groups x 2 k-halves
  bf16x8 afr[16];
  {
    const u32x4* AF4 = (const u32x4*)AF;
    #pragma unroll
    for (int f = 0; f < 16; ++f) {
      u32x4 v = AF4[lane * 16 + f];
      __builtin_memcpy(&afr[f], &v, 16);
    }
  }

  const f32x4* x4 = (const f32x4*)x;
  const int kk = t >> 4, c4s = t & 15;  // staging coords: rows kk+16s, f32x4 col c4s

  f32x4 st[4];
  #pragma unroll
  for (int s = 0; s < 4; ++s)
    st[s] = x4[(kk + 16 * s) * (SN / 4) + (cb0 >> 2) + c4s];
  #pragma unroll
  for (int s = 0; s < 4; ++s) {
    const int base = (kk + 16 * s) * 65 + 4 * c4s;
    Xs[0][base + 0] = st[s][0]; Xs[0][base + 1] = st[s][1];
    Xs[0][base + 2] = st[s][2]; Xs[0][base + 3] = st[s][3];
  }
  __syncthreads();

  for (int ci = 0; ci < 4; ++ci) {
    const int buf = ci & 1;
    if (ci < 3) {
      #pragma unroll
      for (int s = 0; s < 4; ++s)
        st[s] = x4[(kk + 16 * s) * (SN / 4) + (cb0 >> 2) + (ci + 1) * 16 + c4s];
    }

    f32x4 acc[4];
    #pragma unroll
    for (int g = 0; g < 4; ++g) acc[g] = (f32x4){0.f, 0.f, 0.f, 0.f};

    const int c = w * 16 + l15;  // LDS col
    #pragma unroll
    for (int ks = 0; ks < 2; ++ks) {
      bf16x8 bh, bl;
      #pragma unroll
      for (int j2 = 0; j2 < 4; ++j2) {
        const int krow = lg * 8 + 2 * j2 + 32 * ks;
        const float v0 = Xs[buf][krow * 65 + c];
        const float v1 = Xs[buf][(krow + 1) * 65 + c];
        const unsigned short h0 = f2bf(v0), h1 = f2bf(v1);
        const unsigned short q0 = f2bf(v0 - bf2f(h0)), q1 = f2bf(v1 - bf2f(h1));
        bh[2 * j2] = (short)h0; bh[2 * j2 + 1] = (short)h1;
        bl[2 * j2] = (short)q0; bl[2 * j2 + 1] = (short)q1;
      }
      #pragma unroll
      for (int g = 0; g < 4; ++g) {
        const bf16x8 ah = afr[(g * 2 + ks) * 2 + 0];
        const bf16x8 al = afr[(g * 2 + ks) * 2 + 1];
        acc[g] = __builtin_amdgcn_mfma_f32_16x16x32_bf16(ah, bh, acc[g], 0, 0, 0);
        acc[g] = __builtin_amdgcn_mfma_f32_16x16x32_bf16(ah, bl, acc[g], 0, 0, 0);
        acc[g] = __builtin_amdgcn_mfma_f32_16x16x32_bf16(al, bh, acc[g], 0, 0, 0);
      }
    }

    // epilogue: C/D layout col = lane&15, row = (lane>>4)*4 + reg  [m89 verified]
    const int col = cb0 + ci * 64 + w * 16 + l15;
    #pragma unroll
    for (int g = 0; g < 4; ++g)
      #pragma unroll
      for (int ri = 0; ri < 4; ++ri)
        out[(16 * g + lg * 4 + ri) * SN + col] = acc[g][ri];

    if (ci < 3) {
      #pragma unroll
      for (int s = 0; s < 4; ++s) {
        const int base = ((ci + 1) & 1) * 4160 + (kk + 16 * s) * 65 + 4 * c4s;
        ((float*)Xs)[base + 0] = st[s][0]; ((float*)Xs)[base + 1] = st[s][1];
        ((float*)Xs)[base + 2] = st[s][2]; ((float*)Xs)[base + 3] = st[s][3];
      }
      __syncthreads();
    }
  }
}

extern "C" void kernel_launch(void* const* d_in, const int* in_sizes, int n_in,
                              void* d_out, int out_size, void* d_ws, size_t ws_size,
                              hipStream_t stream) {
  const float* x = (const float*)d_in[0];  // 524288 x 64
  const float* L = (const float*)d_in[1];  // 128 x 128
  const float* R = (const float*)d_in[2];  // 64 x 64
  float* out = (float*)d_out;
  float* Ct = (float*)d_ws;                        // 128*64 f32 = 32 KB
  unsigned int* AF = (unsigned int*)(Ct + 128 * 64);  // 64*64 u32 = 16 KB
  k_buildC<<<32, 256, 0, stream>>>(L, R, Ct);
  k_solve<<<1, 256, 0, stream>>>(Ct, AF);
  k_apply<<<2048, 256, 0, stream>>>(x, AF, out);
}